// Round 4
// baseline (552.368 us; speedup 1.0000x reference)
//
#include <hip/hip_runtime.h>

#define D 64
#define KCODES 1024
#define MARGIN 1.5f   // worst-case fp16 gap error <= ~0.6; 2.5x cushion

typedef _Float16 f16x8 __attribute__((ext_vector_type(8)));
typedef float f32x4 __attribute__((ext_vector_type(4)));

// ws layout:
//   [0, 8KB)        e2[1024] fp32 + 16-float zero pad (prefetch overrun)
//   [8KB, 148KB)    ehf[1024*64] fp16 + 4KB pad (prefetch overrun)
#define WS_E2 0
#define WS_EHF 8192

// k0: e2[k] = ||e_k||^2 exact fp32 (round-2/3-proven arithmetic) + fp16 cast
// of the codebook + zero the e2 prefetch pad. grid = 1024*64/256 = 256.
__global__ __launch_bounds__(256) void prep_kernel(const float* __restrict__ emb,
                                                   float* __restrict__ e2,
                                                   _Float16* __restrict__ ehf) {
    int t = blockIdx.x * 256 + threadIdx.x;
    if (t < KCODES) {
        const float4* ep = (const float4*)(emb + (size_t)t * D);
        float s0 = 0.f, s1 = 0.f, s2 = 0.f, s3 = 0.f;
#pragma unroll
        for (int i = 0; i < 16; ++i) {
            float4 v = ep[i];
            s0 = fmaf(v.x, v.x, s0);
            s1 = fmaf(v.y, v.y, s1);
            s2 = fmaf(v.z, v.z, s2);
            s3 = fmaf(v.w, v.w, s3);
        }
        e2[t] = (s0 + s1) + (s2 + s3);
    }
    if (t < 16) e2[KCODES + t] = 0.f;   // prefetch pad
    ehf[t] = (_Float16)emb[t];
}

// k1: fp16-MFMA approx argmin + in-block exact rescore of margin-flagged rows
// + fused epilogue. Block = 4 waves; wave = 32 rows (2 rowsets x 16); grid =
// nrows/128 = 1024 blocks -> 4 waves/SIMD (2x round-3 occupancy).
__global__ __launch_bounds__(256, 4) void vq_kernel(
    const float* __restrict__ x, const float* __restrict__ emb,
    const float* __restrict__ e2, const _Float16* __restrict__ ehf,
    float* __restrict__ out_q, float* __restrict__ out_idx,
    float* __restrict__ out_loss) {
    __shared__ int s_bi[128];
    __shared__ int s_flag[128];
    __shared__ int s_nflag;
    __shared__ float s_d[256];
    __shared__ int s_i[256];

    const int tid = threadIdx.x;
    const int lane = tid & 63;
    const int wave = __builtin_amdgcn_readfirstlane(tid >> 6);
    const int quad = lane >> 4;
    const int l15 = lane & 15;
    const int rowBase = blockIdx.x * 128 + wave * 32;

    if (tid == 0) s_nflag = 0;

    // A fragments: 2 rowsets x 2 K-chunks, fp16. A[m=lane&15][k=quad*8+j].
    f16x8 a[2][2];
#pragma unroll
    for (int rs = 0; rs < 2; ++rs) {
        const float* xr = x + (size_t)(rowBase + rs * 16 + l15) * D;
#pragma unroll
        for (int c = 0; c < 2; ++c) {
            const float4* p = (const float4*)(xr + c * 32 + quad * 8);
            float4 f0 = p[0], f1 = p[1];
            f16x8 h;
            h[0] = (_Float16)f0.x; h[1] = (_Float16)f0.y;
            h[2] = (_Float16)f0.z; h[3] = (_Float16)f0.w;
            h[4] = (_Float16)f1.x; h[5] = (_Float16)f1.y;
            h[6] = (_Float16)f1.z; h[7] = (_Float16)f1.w;
            a[rs][c] = h;
        }
    }

    float m1[2][4], m2[2][4];
    int i1[2][4];
#pragma unroll
    for (int rs = 0; rs < 2; ++rs)
#pragma unroll
        for (int r = 0; r < 4; ++r) {
            m1[rs][r] = 3.4e38f;
            m2[rs][r] = 3.4e38f;
            i1[rs][r] = 0;
        }

    // B: code t*16+l15, fragment B[n=l15][k=quad*8+j]; register-rotated
    // prefetch of tile t+1 (pad regions make the t=63 overrun safe).
    const _Float16* bbase = ehf + (size_t)l15 * D + quad * 8;
    f16x8 nb0 = *(const f16x8*)(bbase);
    f16x8 nb1 = *(const f16x8*)(bbase + 32);
    float ne2 = e2[l15];
    for (int t = 0; t < 64; ++t) {
        f16x8 b0 = nb0, b1 = nb1;
        float e2v = ne2;
        const _Float16* nb = bbase + (size_t)(t + 1) * 16 * D;
        nb0 = *(const f16x8*)(nb);
        nb1 = *(const f16x8*)(nb + 32);
        ne2 = e2[(t + 1) * 16 + l15];
        const int code = (t << 4) + l15;
#pragma unroll
        for (int rs = 0; rs < 2; ++rs) {
            f32x4 acc = {0.f, 0.f, 0.f, 0.f};
            acc = __builtin_amdgcn_mfma_f32_16x16x32_f16(a[rs][0], b0, acc, 0, 0, 0);
            acc = __builtin_amdgcn_mfma_f32_16x16x32_f16(a[rs][1], b1, acc, 0, 0, 0);
#pragma unroll
            for (int r = 0; r < 4; ++r) {
                float v = fmaf(-2.0f, acc[r], e2v);
                bool take = v < m1[rs][r];               // ascending t: first-min
                i1[rs][r] = take ? code : i1[rs][r];
                m2[rs][r] = fminf(m2[rs][r], fmaxf(m1[rs][r], v));
                m1[rs][r] = fminf(m1[rs][r], v);
            }
        }
    }

    // Merge across the 16 code-lanes (masks 1,2,4,8 stay inside the quad).
#pragma unroll
    for (int rs = 0; rs < 2; ++rs)
#pragma unroll
        for (int r = 0; r < 4; ++r) {
            float v1 = m1[rs][r], v2 = m2[rs][r];
            int ix = i1[rs][r];
#pragma unroll
            for (int mask = 1; mask < 16; mask <<= 1) {
                float o1 = __shfl_xor(v1, mask);
                int oi = __shfl_xor(ix, mask);
                float o2 = __shfl_xor(v2, mask);
                v2 = fminf(fminf(v2, o2), fmaxf(v1, o1));   // union 2nd-min
                bool take = (o1 < v1) || (o1 == v1 && oi < ix);
                v1 = take ? o1 : v1;
                ix = take ? oi : ix;
            }
            m1[rs][r] = v1;
            m2[rs][r] = v2;
            i1[rs][r] = ix;
        }

    if (l15 == 0) {   // writer lanes: rows quad*4+r of each rowset
#pragma unroll
        for (int rs = 0; rs < 2; ++rs)
#pragma unroll
            for (int r = 0; r < 4; ++r) {
                int lrow = wave * 32 + rs * 16 + quad * 4 + r;
                s_bi[lrow] = i1[rs][r];
                if (m2[rs][r] - m1[rs][r] < MARGIN) {
                    int slot = atomicAdd(&s_nflag, 1);
                    s_flag[slot] = lrow;
                }
            }
    }
    __syncthreads();

    // In-block exact fp32 rescore of flagged rows (round-2/3-proven formula
    // and first-min tie-break), BEFORE the epilogue.
    const int nf = s_nflag;
    for (int f = 0; f < nf; ++f) {
        const int lrow = s_flag[f];
        const int row = blockIdx.x * 128 + lrow;
        const float* xr = x + (size_t)row * D;
        float xv[D];
        const float4* xp = (const float4*)xr;
#pragma unroll
        for (int i = 0; i < 16; ++i) {
            float4 v = xp[i];
            xv[4 * i + 0] = v.x;
            xv[4 * i + 1] = v.y;
            xv[4 * i + 2] = v.z;
            xv[4 * i + 3] = v.w;
        }
        float bd = 3.4e38f;
        int bi = 0;
        for (int kk = 0; kk < 4; ++kk) {
            const int k = tid + kk * 256;   // ascending per thread
            const float* ek = emb + (size_t)k * D;
            float d0 = 0.f, d1 = 0.f, d2 = 0.f, d3 = 0.f;
#pragma unroll
            for (int i = 0; i < 16; ++i) {
                d0 = fmaf(xv[4 * i + 0], ek[4 * i + 0], d0);
                d1 = fmaf(xv[4 * i + 1], ek[4 * i + 1], d1);
                d2 = fmaf(xv[4 * i + 2], ek[4 * i + 2], d2);
                d3 = fmaf(xv[4 * i + 3], ek[4 * i + 3], d3);
            }
            float dist = fmaf(-2.0f, (d0 + d1) + (d2 + d3), e2[k]);
            if (dist < bd) { bd = dist; bi = k; }
        }
        s_d[tid] = bd;
        s_i[tid] = bi;
        __syncthreads();
        for (int s = 128; s > 0; s >>= 1) {
            if (tid < s) {
                float od = s_d[tid + s];
                int oi = s_i[tid + s];
                if (od < s_d[tid] || (od == s_d[tid] && oi < s_i[tid])) {
                    s_d[tid] = od;
                    s_i[tid] = oi;
                }
            }
            __syncthreads();
        }
        if (tid == 0) s_bi[lrow] = s_i[0];
        __syncthreads();
    }

    // Epilogue (round-2/3-proven arithmetic): one row per thread, 128 rows.
    if (tid < 128) {
        const int row = blockIdx.x * 128 + tid;
        const int bi = s_bi[tid];
        const float4* qp = (const float4*)(emb + (size_t)bi * D);
        const float4* xp = (const float4*)(x + (size_t)row * D);
        float4* oq = (float4*)(out_q + (size_t)row * D);
        float l0 = 0.f, l1 = 0.f, l2 = 0.f, l3 = 0.f;
#pragma unroll
        for (int i = 0; i < 16; ++i) {
            float4 q = qp[i];
            float4 xv = xp[i];
            float a0 = q.x - xv.x, a1 = q.y - xv.y, a2 = q.z - xv.z, a3 = q.w - xv.w;
            l0 = fmaf(a0, a0, l0);
            l1 = fmaf(a1, a1, l1);
            l2 = fmaf(a2, a2, l2);
            l3 = fmaf(a3, a3, l3);
            float4 o;
            o.x = xv.x + a0;
            o.y = xv.y + a1;
            o.z = xv.z + a2;
            o.w = xv.w + a3;
            oq[i] = o;
        }
        float s = (l0 + l1) + (l2 + l3);
        out_idx[row] = (float)bi;
        out_loss[row] = s + 0.25f * s;
    }
}

extern "C" void kernel_launch(void* const* d_in, const int* in_sizes, int n_in,
                              void* d_out, int out_size, void* d_ws, size_t ws_size,
                              hipStream_t stream) {
    const float* x = (const float*)d_in[0];     // [B,T,D] fp32
    const float* emb = (const float*)d_in[1];   // [K,D] fp32
    const int nrows = in_sizes[0] / D;          // 131072

    float* out_q = (float*)d_out;
    float* out_idx = out_q + (size_t)nrows * D;
    float* out_loss = out_idx + nrows;

    char* ws = (char*)d_ws;
    float* e2 = (float*)(ws + WS_E2);
    _Float16* ehf = (_Float16*)(ws + WS_EHF);

    prep_kernel<<<(KCODES * D) / 256, 256, 0, stream>>>(emb, e2, ehf);
    vq_kernel<<<nrows / 128, 256, 0, stream>>>(x, emb, e2, ehf, out_q, out_idx,
                                               out_loss);
}

// Round 5
// 447.919 us; speedup vs baseline: 1.2332x; 1.2332x over previous
//
#include <hip/hip_runtime.h>

#define D 64
#define KCODES 1024
#define MARGIN 1.5f      // worst-case fp16 distance-gap error <= ~0.6; 2.5x cushion
#define FLAG_CAP 16384

typedef _Float16 f16x8 __attribute__((ext_vector_type(8)));
typedef float f32x4 __attribute__((ext_vector_type(4)));

// ws layout:
//   [0, 8KB)                 e2[1024] fp32 + zeroed prefetch pad
//   [8KB, 8KB+128KB+4KB)     ehf[1024*64] fp16 + prefetch pad (t=63 nb1 reads +64B past 2KB)
//   [143360, +64)            flag counter
//   [143424, +64KB)          flag list
#define WS_E2 0
#define WS_EHF 8192
#define WS_CNT 143360
#define WS_FLAGS 143424

// k0: exact fp32 e2 (round-2/3-proven) + fp16 codebook cast + counter zero.
__global__ __launch_bounds__(256) void prep_kernel(const float* __restrict__ emb,
                                                   float* __restrict__ e2,
                                                   _Float16* __restrict__ ehf,
                                                   unsigned int* __restrict__ counter) {
    int t = blockIdx.x * 256 + threadIdx.x;
    if (t == 0) *counter = 0u;
    if (t < KCODES) {
        const float4* ep = (const float4*)(emb + (size_t)t * D);
        float s0 = 0.f, s1 = 0.f, s2 = 0.f, s3 = 0.f;
#pragma unroll
        for (int i = 0; i < 16; ++i) {
            float4 v = ep[i];
            s0 = fmaf(v.x, v.x, s0);
            s1 = fmaf(v.y, v.y, s1);
            s2 = fmaf(v.z, v.z, s2);
            s3 = fmaf(v.w, v.w, s3);
        }
        e2[t] = (s0 + s1) + (s2 + s3);
    }
    if (t < 16) e2[KCODES + t] = 0.f;   // e2 prefetch pad
    ehf[t] = (_Float16)emb[t];
}

// k1: fp16-MFMA approx argmin + margin flag to global list + fused epilogue.
// Block = 4 waves x 32 rows; grid = nrows/128 = 1024 blocks. No register
// arrays beyond the MFMA fragments -> no scratch (round-4 spill fix).
__global__ __launch_bounds__(256, 4) void vq_kernel(
    const float* __restrict__ x, const float* __restrict__ emb,
    const float* __restrict__ e2, const _Float16* __restrict__ ehf,
    float* __restrict__ out_q, float* __restrict__ out_idx,
    float* __restrict__ out_loss, unsigned int* __restrict__ counter,
    int* __restrict__ flaglist) {
    __shared__ int s_bi[128];
    const int tid = threadIdx.x;
    const int lane = tid & 63;
    const int wave = __builtin_amdgcn_readfirstlane(tid >> 6);
    const int quad = lane >> 4;
    const int l15 = lane & 15;
    const int rowBase = blockIdx.x * 128 + wave * 32;

    // A fragments: 2 rowsets x 2 K-chunks, fp16. A[m=lane&15][k=quad*8+j].
    f16x8 a[2][2];
#pragma unroll
    for (int rs = 0; rs < 2; ++rs) {
        const float* xr = x + (size_t)(rowBase + rs * 16 + l15) * D;
#pragma unroll
        for (int c = 0; c < 2; ++c) {
            const float4* p = (const float4*)(xr + c * 32 + quad * 8);
            float4 f0 = p[0], f1 = p[1];
            f16x8 h;
            h[0] = (_Float16)f0.x; h[1] = (_Float16)f0.y;
            h[2] = (_Float16)f0.z; h[3] = (_Float16)f0.w;
            h[4] = (_Float16)f1.x; h[5] = (_Float16)f1.y;
            h[6] = (_Float16)f1.z; h[7] = (_Float16)f1.w;
            a[rs][c] = h;
        }
    }

    float m1[2][4], m2[2][4];
    int i1[2][4];
#pragma unroll
    for (int rs = 0; rs < 2; ++rs)
#pragma unroll
        for (int r = 0; r < 4; ++r) {
            m1[rs][r] = 3.4e38f;
            m2[rs][r] = 3.4e38f;
            i1[rs][r] = 0;
        }

    // B: code t*16+l15, B[n=l15][k=quad*8+j]; register-rotated prefetch of
    // tile t+1 (pads make the final overrun-read safe; values unused).
    const _Float16* bbase = ehf + (size_t)l15 * D + quad * 8;
    f16x8 nb0 = *(const f16x8*)(bbase);
    f16x8 nb1 = *(const f16x8*)(bbase + 32);
    float ne2 = e2[l15];
    for (int t = 0; t < 64; ++t) {
        f16x8 b0 = nb0, b1 = nb1;
        float e2v = ne2;
        const _Float16* nb = bbase + (size_t)(t + 1) * 16 * D;
        nb0 = *(const f16x8*)(nb);
        nb1 = *(const f16x8*)(nb + 32);
        ne2 = e2[(t + 1) * 16 + l15];
        const int code = (t << 4) + l15;
#pragma unroll
        for (int rs = 0; rs < 2; ++rs) {
            f32x4 acc = {0.f, 0.f, 0.f, 0.f};
            acc = __builtin_amdgcn_mfma_f32_16x16x32_f16(a[rs][0], b0, acc, 0, 0, 0);
            acc = __builtin_amdgcn_mfma_f32_16x16x32_f16(a[rs][1], b1, acc, 0, 0, 0);
#pragma unroll
            for (int r = 0; r < 4; ++r) {
                float v = fmaf(-2.0f, acc[r], e2v);
                bool take = v < m1[rs][r];               // ascending t: first-min
                i1[rs][r] = take ? code : i1[rs][r];
                m2[rs][r] = fminf(m2[rs][r], fmaxf(m1[rs][r], v));
                m1[rs][r] = fminf(m1[rs][r], v);
            }
        }
    }

    // Merge across the 16 code-lanes.
#pragma unroll
    for (int rs = 0; rs < 2; ++rs)
#pragma unroll
        for (int r = 0; r < 4; ++r) {
            float v1 = m1[rs][r], v2 = m2[rs][r];
            int ix = i1[rs][r];
#pragma unroll
            for (int mask = 1; mask < 16; mask <<= 1) {
                float o1 = __shfl_xor(v1, mask);
                int oi = __shfl_xor(ix, mask);
                float o2 = __shfl_xor(v2, mask);
                v2 = fminf(fminf(v2, o2), fmaxf(v1, o1));   // union 2nd-min
                bool take = (o1 < v1) || (o1 == v1 && oi < ix);
                v1 = take ? o1 : v1;
                ix = take ? oi : ix;
            }
            m1[rs][r] = v1;
            m2[rs][r] = v2;
            i1[rs][r] = ix;
        }

    if (l15 == 0) {   // writer lanes: rows quad*4+r of each rowset
#pragma unroll
        for (int rs = 0; rs < 2; ++rs)
#pragma unroll
            for (int r = 0; r < 4; ++r) {
                int lrow = wave * 32 + rs * 16 + quad * 4 + r;
                s_bi[lrow] = i1[rs][r];
                if (m2[rs][r] - m1[rs][r] < MARGIN) {
                    unsigned int slot = atomicAdd(counter, 1u);
                    if (slot < FLAG_CAP) flaglist[slot] = blockIdx.x * 128 + lrow;
                }
            }
    }
    __syncthreads();

    // Fused epilogue (round-2/3/4-proven arithmetic): one row per thread.
    if (tid < 128) {
        const int row = blockIdx.x * 128 + tid;
        const int bi = s_bi[tid];
        const float4* qp = (const float4*)(emb + (size_t)bi * D);
        const float4* xp = (const float4*)(x + (size_t)row * D);
        float4* oq = (float4*)(out_q + (size_t)row * D);
        float l0 = 0.f, l1 = 0.f, l2 = 0.f, l3 = 0.f;
#pragma unroll
        for (int i = 0; i < 16; ++i) {
            float4 q = qp[i];
            float4 xv = xp[i];
            float a0 = q.x - xv.x, a1 = q.y - xv.y, a2 = q.z - xv.z, a3 = q.w - xv.w;
            l0 = fmaf(a0, a0, l0);
            l1 = fmaf(a1, a1, l1);
            l2 = fmaf(a2, a2, l2);
            l3 = fmaf(a3, a3, l3);
            float4 o;
            o.x = xv.x + a0;
            o.y = xv.y + a1;
            o.z = xv.z + a2;
            o.w = xv.w + a3;
            oq[i] = o;
        }
        float s = (l0 + l1) + (l2 + l3);
        out_idx[row] = (float)bi;
        out_loss[row] = s + 0.25f * s;
    }
}

// k2: exact fp32 rescore, one WAVE per flagged row (grid-stride). Lane l
// scans codes j*64+l; cross-lane lex-min (dist, idx) preserves jnp.argmin
// first-min. Epilogue on lane 0 uses the bit-identical summation structure.
__global__ __launch_bounds__(256) void rescore_kernel(
    const float* __restrict__ x, const float* __restrict__ emb,
    const float* __restrict__ e2, float* __restrict__ out_q,
    float* __restrict__ out_idx, float* __restrict__ out_loss,
    const unsigned int* __restrict__ counter, const int* __restrict__ flaglist) {
    unsigned int n = *counter;
    if (n > FLAG_CAP) n = FLAG_CAP;
    const int lane = threadIdx.x & 63;
    const int gwave = (blockIdx.x * 256 + threadIdx.x) >> 6;
    const int nwaves = gridDim.x * 4;

    for (unsigned int f = gwave; f < n; f += nwaves) {
        const int row = flaglist[f];
        const float* xr = x + (size_t)row * D;
        float xv[D];   // full row per lane (broadcast loads; own kernel -> no spill)
        const float4* xp = (const float4*)xr;
#pragma unroll
        for (int i = 0; i < 16; ++i) {
            float4 v = xp[i];
            xv[4 * i + 0] = v.x;
            xv[4 * i + 1] = v.y;
            xv[4 * i + 2] = v.z;
            xv[4 * i + 3] = v.w;
        }
        float bd = 3.4e38f;
        int bi = 0;
        for (int j = 0; j < 16; ++j) {
            const int k = j * 64 + lane;   // ascending per lane
            const float* ek = emb + (size_t)k * D;
            float d0 = 0.f, d1 = 0.f, d2 = 0.f, d3 = 0.f;
#pragma unroll
            for (int i = 0; i < 16; ++i) {
                d0 = fmaf(xv[4 * i + 0], ek[4 * i + 0], d0);
                d1 = fmaf(xv[4 * i + 1], ek[4 * i + 1], d1);
                d2 = fmaf(xv[4 * i + 2], ek[4 * i + 2], d2);
                d3 = fmaf(xv[4 * i + 3], ek[4 * i + 3], d3);
            }
            float dist = fmaf(-2.0f, (d0 + d1) + (d2 + d3), e2[k]);
            if (dist < bd) { bd = dist; bi = k; }   // exact fp32, proven formula
        }
        // 64-lane lex-min butterfly on (bd, bi).
#pragma unroll
        for (int mask = 1; mask < 64; mask <<= 1) {
            float od = __shfl_xor(bd, mask);
            int oi = __shfl_xor(bi, mask);
            bool take = (od < bd) || (od == bd && oi < bi);
            bd = take ? od : bd;
            bi = take ? oi : bi;
        }
        if (lane == 0) {   // bit-identical epilogue for this row
            const float4* qp = (const float4*)(emb + (size_t)bi * D);
            float4* oq = (float4*)(out_q + (size_t)row * D);
            float l0 = 0.f, l1 = 0.f, l2 = 0.f, l3 = 0.f;
#pragma unroll
            for (int i = 0; i < 16; ++i) {
                float4 q = qp[i];
                float4 xw = xp[i];
                float a0 = q.x - xw.x, a1 = q.y - xw.y, a2 = q.z - xw.z, a3 = q.w - xw.w;
                l0 = fmaf(a0, a0, l0);
                l1 = fmaf(a1, a1, l1);
                l2 = fmaf(a2, a2, l2);
                l3 = fmaf(a3, a3, l3);
                float4 o;
                o.x = xw.x + a0;
                o.y = xw.y + a1;
                o.z = xw.z + a2;
                o.w = xw.w + a3;
                oq[i] = o;
            }
            float s = (l0 + l1) + (l2 + l3);
            out_idx[row] = (float)bi;
            out_loss[row] = s + 0.25f * s;
        }
    }
}

extern "C" void kernel_launch(void* const* d_in, const int* in_sizes, int n_in,
                              void* d_out, int out_size, void* d_ws, size_t ws_size,
                              hipStream_t stream) {
    const float* x = (const float*)d_in[0];     // [B,T,D] fp32
    const float* emb = (const float*)d_in[1];   // [K,D] fp32
    const int nrows = in_sizes[0] / D;          // 131072

    float* out_q = (float*)d_out;
    float* out_idx = out_q + (size_t)nrows * D;
    float* out_loss = out_idx + nrows;

    char* ws = (char*)d_ws;
    float* e2 = (float*)(ws + WS_E2);
    _Float16* ehf = (_Float16*)(ws + WS_EHF);
    unsigned int* counter = (unsigned int*)(ws + WS_CNT);
    int* flaglist = (int*)(ws + WS_FLAGS);

    prep_kernel<<<(KCODES * D) / 256, 256, 0, stream>>>(emb, e2, ehf, counter);
    vq_kernel<<<nrows / 128, 256, 0, stream>>>(x, emb, e2, ehf, out_q, out_idx,
                                               out_loss, counter, flaglist);
    rescore_kernel<<<256, 256, 0, stream>>>(x, emb, e2, out_q, out_idx, out_loss,
                                            counter, flaglist);
}